// Round 12
// baseline (997.368 us; speedup 1.0000x reference)
//
#include <hip/hip_runtime.h>
#include <hip/hip_bf16.h>
#include <cstdint>
#include <cstddef>

typedef __bf16 bf16_t;
typedef __bf16 bf16x8 __attribute__((ext_vector_type(8)));
typedef float f32x4 __attribute__((ext_vector_type(4)));

#define GLP(p)  (const __attribute__((address_space(1))) void*)(p)
#define LDSP(p) (__attribute__((address_space(3))) void*)(p)

static constexpr int BS   = 8;
static constexpr int SEQ  = 2048;
static constexpr int DIN  = 4096;
static constexpr int DOUT = 4096;
static constexpr int NSK  = 8;
static constexpr int RANK = 16;
static constexpr int MTOT = BS * SEQ;           // 16384

static __device__ __forceinline__ bf16x8 cvt8(float4 v0, float4 v1) {
    bf16x8 o;
    o[0] = (bf16_t)v0.x; o[1] = (bf16_t)v0.y; o[2] = (bf16_t)v0.z; o[3] = (bf16_t)v0.w;
    o[4] = (bf16_t)v1.x; o[5] = (bf16_t)v1.y; o[6] = (bf16_t)v1.z; o[7] = (bf16_t)v1.w;
    return o;
}

// ------------------------------------------------------------------
// Kernel 1: mixing weights
// ------------------------------------------------------------------
__global__ __launch_bounds__(256) void mix_kernel(
    const float* __restrict__ logits, const int* __restrict__ task_ids,
    const float* __restrict__ lora_a, const float* __restrict__ lora_b,
    bf16_t* __restrict__ Abt, bf16_t* __restrict__ Btp) {
    int b = blockIdx.y;
    int c = blockIdx.x;
    int tid = threadIdx.x;

    int t = task_ids[b];
    float w[NSK]; float sum = 0.f;
#pragma unroll
    for (int s = 0; s < NSK; ++s) {
        float lg = logits[t * NSK + s];
        float sg = 1.f / (1.f + __expf(-lg));
        w[s] = sg; sum += sg;
    }
    float inv = 1.f / (sum + 1e-12f);
#pragma unroll
    for (int s = 0; s < NSK; ++s) w[s] *= inv;

    {
        int r = tid & 15, kk = tid >> 4;
#pragma unroll
        for (int i = 0; i < 4; ++i) {
            int k = c * 64 + i * 16 + kk;
            float acc = 0.f;
#pragma unroll
            for (int s = 0; s < NSK; ++s)
                acc += w[s] * lora_a[((size_t)s * DIN + k) * RANK + r];
            Abt[((size_t)b * RANK + r) * DIN + k] = (bf16_t)acc;
        }
    }
    {
        int n = c * 64 + (tid & 63);
        int r0 = tid >> 6;
#pragma unroll
        for (int i = 0; i < 4; ++i) {
            int rr = r0 + i * 4;
            float acc = 0.f;
#pragma unroll
            for (int s = 0; s < NSK; ++s)
                acc += w[s] * lora_b[((size_t)s * RANK + rr) * DOUT + n];
            Btp[((size_t)b * DOUT + n) * 32 + rr] = (bf16_t)acc;
            Btp[((size_t)b * DOUT + n) * 32 + 16 + rr] = (bf16_t)0.f;
        }
    }
}

// ------------------------------------------------------------------
// Kernel 2: W f32 -> bf16
// ------------------------------------------------------------------
__global__ __launch_bounds__(256) void convw_kernel(const float* __restrict__ W,
                                                    bf16_t* __restrict__ Wb) {
    size_t g = (size_t)blockIdx.x * 256 + threadIdx.x;
    const float4* src = (const float4*)W;
    float4 v0 = src[g * 2], v1 = src[g * 2 + 1];
    *(bf16x8*)(Wb + g * 8) = cvt8(v0, v1);
}

// ------------------------------------------------------------------
// Kernel 3: fused x->bf16 conversion + t = (x @ A_mix)/16, padded to K=32
// ------------------------------------------------------------------
template<bool XPRE>
__global__ __launch_bounds__(256) void tconv_kernel(
    const float* __restrict__ x, const bf16_t* __restrict__ Abt,
    bf16_t* __restrict__ xb, bf16_t* __restrict__ tpad) {
    __shared__ __align__(16) bf16_t As[64 * 64];
    __shared__ __align__(16) bf16_t Aa[16 * 64];

    int row0 = blockIdx.x * 64;
    int b = row0 >> 11;
    int tid = threadIdx.x;
    int w = tid >> 6, l = tid & 63;
    const bf16_t* Ab = Abt + (size_t)b * RANK * DIN;

    f32x4 acc = {0.f, 0.f, 0.f, 0.f};

    for (int k0 = 0; k0 < DIN; k0 += 64) {
#pragma unroll
        for (int i = 0; i < 2; ++i) {
            int flat = i * 256 + tid;
            int row = flat >> 3, c8 = flat & 7;
            const float* src = x + (size_t)(row0 + row) * DIN + k0 + c8 * 8;
            float4 v0 = *(const float4*)src;
            float4 v1 = *(const float4*)(src + 4);
            bf16x8 o = cvt8(v0, v1);
            *(bf16x8*)(&As[flat * 8]) = o;
            if (XPRE)
                *(bf16x8*)(xb + (size_t)(row0 + row) * DIN + k0 + c8 * 8) = o;
        }
        if (tid < 128) {
            int r = tid >> 3, c8 = tid & 7;
            __builtin_amdgcn_global_load_lds(GLP(Ab + (size_t)r * DIN + k0 + c8 * 8),
                                             LDSP(&Aa[tid * 8]), 16, 0, 0);
        }
        __syncthreads();
#pragma unroll
        for (int s = 0; s < 2; ++s) {
            int kr = s * 32 + (l >> 4) * 8;
            bf16x8 a = *(const bf16x8*)(&As[(w * 16 + (l & 15)) * 64 + kr]);
            bf16x8 bb = *(const bf16x8*)(&Aa[(l & 15) * 64 + kr]);
            acc = __builtin_amdgcn_mfma_f32_16x16x32_bf16(a, bb, acc, 0, 0, 0);
        }
        __syncthreads();
    }
    int r = l & 15;
    int rowb = w * 16 + (l >> 4) * 4;
#pragma unroll
    for (int j = 0; j < 4; ++j) {
        int gm = row0 + rowb + j;
        tpad[(size_t)gm * 32 + r] = (bf16_t)(acc[j] * 0.0625f);
        tpad[(size_t)gm * 32 + 16 + r] = (bf16_t)0.f;
    }
}

// ------------------------------------------------------------------
// Kernel 4: 256x256 GEMM — 4 phases/tile, ONE barrier/phase, fragment
//   reads ONE PHASE AHEAD with counted lgkm drains (m201 mechanism).
//   LDS: [parity][slot: A0,A1,B0,B1][128x64] bf16 = 128 KiB.
//   Phase reads:  ph0: bA+bB(t)   ph1: aB(t)   ph2: —    ph3: aA(t+1)
//   lgkm before MFMA: 4 / 8 / 0 / none.
//   Stage (1 chunk/phase): ph0->B1(t+1) ph1->A1(t+1) ph2->A0(t+2) ph3->B0(t+2)
//   vmcnt guards (pre-barrier): ph0:6  ph1:—  ph2:8  ph3:6  (4-5 phase leads)
// ------------------------------------------------------------------
#define LGKM0  asm volatile("s_waitcnt lgkmcnt(0)" ::: "memory")
#define SBAR   __builtin_amdgcn_s_barrier()
#define SCHEDB __builtin_amdgcn_sched_barrier(0)
#define PRIO1  __builtin_amdgcn_s_setprio(1)
#define PRIO0  __builtin_amdgcn_s_setprio(0)
#define VMG(TXT) asm volatile("s_waitcnt " TXT ::: "memory")

#define MFMA_Q(AREG, BREG, QM, QN)                                             \
    _Pragma("unroll") for (int s_ = 0; s_ < 2; ++s_)                           \
    _Pragma("unroll") for (int i_ = 0; i_ < 4; ++i_)                           \
    _Pragma("unroll") for (int jj_ = 0; jj_ < 2; ++jj_)                        \
        acc[(QM)*4 + i_][(QN)*2 + jj_] =                                       \
            __builtin_amdgcn_mfma_f32_16x16x32_bf16(                           \
                AREG[i_][s_], BREG[jj_][s_], acc[(QM)*4 + i_][(QN)*2 + jj_],   \
                0, 0, 0);

// One K-tile. P = parity. S0..S3, G0/G2/G3, PH3R are statements.
#define TILE_T(P, S0, S1, S2, S3, G0, G2, G3, PH3R)                            \
  {                                                                            \
    /* ph0: MFMA(0,0) aA,bA ; reads bA,bB(t) */                                \
    loadB(&lds[P][2][0], bA);                                                  \
    loadB(&lds[P][3][0], bB);                                                  \
    S0;                                                                        \
    G0; SCHEDB; SBAR; SCHEDB;                                                  \
    asm volatile("s_waitcnt lgkmcnt(4)" ::: "memory"); SCHEDB;                 \
    PRIO1; MFMA_Q(aA, bA, 0, 0); PRIO0; SCHEDB;                                \
    /* ph1: MFMA(0,1) aA,bB ; reads aB(t) */                                   \
    loadA(&lds[P][1][0], aB);                                                  \
    S1;                                                                        \
    SCHEDB; SBAR; SCHEDB;                                                      \
    asm volatile("s_waitcnt lgkmcnt(8)" ::: "memory"); SCHEDB;                 \
    PRIO1; MFMA_Q(aA, bB, 0, 1); PRIO0; SCHEDB;                                \
    /* ph2: MFMA(1,1) aB,bB */                                                 \
    S2;                                                                        \
    G2; SCHEDB; SBAR; SCHEDB;                                                  \
    LGKM0; SCHEDB;                                                             \
    PRIO1; MFMA_Q(aB, bB, 1, 1); PRIO0; SCHEDB;                                \
    /* ph3: MFMA(1,0) aB,bA ; prefetch aA(t+1) */                              \
    PH3R;                                                                      \
    S3;                                                                        \
    G3; SCHEDB; SBAR; SCHEDB;                                                  \
    PRIO1; MFMA_Q(aB, bA, 1, 0); PRIO0; SCHEDB;                                \
  }

__global__ __launch_bounds__(512, 2) void gemm8_kernel(
    const bf16_t* __restrict__ xb, const bf16_t* __restrict__ Wb,
    const float* __restrict__ bias,
    const bf16_t* __restrict__ tpad, const bf16_t* __restrict__ Btp,
    float* __restrict__ out) {
    __shared__ __align__(16) bf16_t lds[2][4][128 * 64];   // 128 KiB

    int tid = threadIdx.x;
    int w = tid >> 6, l = tid & 63;
    int wm = w >> 2, wn = w & 3;        // 2M x 4N waves
    int l4 = l >> 4, l15 = l & 15;

    // XCD-bijective swizzle: nwg = 1024, 8 XCDs, 128 per XCD
    int orig = blockIdx.x;
    int id = (orig & 7) * 128 + (orig >> 3);
    int mb = id >> 4, nb = id & 15;
    int row0 = mb * 256, col0 = nb * 256;
    int b = row0 >> 11;

    f32x4 acc[8][4] = {};
    bf16x8 aA[4][2], aB[4][2], bA[2][2], bB[2][2];

    auto stageA = [&](int kt, int par, int half) {
        int k0 = kt * 64;
        const bf16_t* src = xb + (size_t)(row0 + half * 128) * DIN;
        bf16_t* dst = &lds[par][half][0];
#pragma unroll
        for (int ld = 0; ld < 2; ++ld) {
            int flat = ld * 512 + tid;
            int r = flat >> 3;
            int sc = (flat & 7) ^ (r & 7);
            __builtin_amdgcn_global_load_lds(
                GLP(src + (size_t)r * DIN + k0 + sc * 8),
                LDSP(dst + flat * 8), 16, 0, 0);
        }
    };
    auto stageB = [&](int kt, int par, int half) {
        int k0 = kt * 64;
        const bf16_t* src = Wb + (size_t)(col0 + half * 128) * DIN;
        bf16_t* dst = &lds[par][2 + half][0];
#pragma unroll
        for (int ld = 0; ld < 2; ++ld) {
            int flat = ld * 512 + tid;
            int r = flat >> 3;
            int sc = (flat & 7) ^ (r & 7);
            __builtin_amdgcn_global_load_lds(
                GLP(src + (size_t)r * DIN + k0 + sc * 8),
                LDSP(dst + flat * 8), 16, 0, 0);
        }
    };
    auto stageAdpA = [&]() {
#pragma unroll
        for (int ld = 0; ld < 2; ++ld) {
            int flat = ld * 512 + tid;
            int r = flat >> 2, c4 = flat & 3;
            __builtin_amdgcn_global_load_lds(
                GLP(tpad + (size_t)(row0 + r) * 32 + c4 * 8),
                LDSP(&lds[0][0][flat * 8]), 16, 0, 0);
        }
    };
    auto stageAdpB = [&]() {
#pragma unroll
        for (int ld = 0; ld < 2; ++ld) {
            int flat = ld * 512 + tid;
            int r = flat >> 2, c4 = flat & 3;
            __builtin_amdgcn_global_load_lds(
                GLP(Btp + ((size_t)b * DOUT + col0 + r) * 32 + c4 * 8),
                LDSP(&lds[0][2][flat * 8]), 16, 0, 0);
        }
    };

    auto loadA = [&](const bf16_t* base, bf16x8 (&ar)[4][2]) {
#pragma unroll
        for (int i = 0; i < 4; ++i) {
            int row = wm * 64 + i * 16 + l15;
#pragma unroll
            for (int s = 0; s < 2; ++s)
                ar[i][s] = *(const bf16x8*)(base + row * 64 +
                                            (((s * 4 + l4) ^ (l15 & 7)) << 3));
        }
    };
    auto loadB = [&](const bf16_t* base, bf16x8 (&br)[2][2]) {
#pragma unroll
        for (int jj = 0; jj < 2; ++jj) {
            int row = wn * 32 + jj * 16 + l15;
#pragma unroll
            for (int s = 0; s < 2; ++s)
                br[jj][s] = *(const bf16x8*)(base + row * 64 +
                                             (((s * 4 + l4) ^ (l15 & 7)) << 3));
        }
    };

    // ---- prologue: issue chunks in steady-state order ----
    stageA(0, 0, 0);      // A0(0)
    stageB(0, 0, 0);      // B0(0)
    stageB(0, 0, 1);      // B1(0)
    stageA(0, 0, 1);      // A1(0)
    stageA(1, 1, 0);      // A0(1)
    stageB(1, 1, 0);      // B0(1)
    VMG("vmcnt(6)");      // A0,B0,B1(0) landed; 3 chunks in flight
    SCHEDB; SBAR; SCHEDB;
    loadA(&lds[0][0][0], aA);   // aA(0), consumed in tile 0 ph0/ph1

#pragma unroll 1
    for (int jj = 0; jj < 31; ++jj) {
        int t0 = jj * 2, t1 = t0 + 1;
        TILE_T(0,
               stageB(t0 + 1, 1, 1), stageA(t0 + 1, 1, 1),
               stageA(t0 + 2, 0, 0), stageB(t0 + 2, 0, 0),
               VMG("vmcnt(6)"), VMG("vmcnt(8)"), VMG("vmcnt(6)"),
               loadA(&lds[1][0][0], aA));
        TILE_T(1,
               stageB(t1 + 1, 0, 1), stageA(t1 + 1, 0, 1),
               stageA(t1 + 2, 1, 0), stageB(t1 + 2, 1, 0),
               VMG("vmcnt(6)"), VMG("vmcnt(8)"), VMG("vmcnt(6)"),
               loadA(&lds[0][0][0], aA));
    }
    // tile 62 (P=0): ph2/ph3 stage the adapter into buf0 A0/B0 slots
    TILE_T(0,
           stageB(63, 1, 1), stageA(63, 1, 1),
           stageAdpA(), stageAdpB(),
           VMG("vmcnt(6)"), VMG("vmcnt(8)"), VMG("vmcnt(6)"),
           loadA(&lds[1][0][0], aA));
    // tile 63 (P=1): peeled — no stages, no next-tile reads
    TILE_T(1,
           , , , ,
           VMG("vmcnt(4)"), , ,
           );

    // drain adapter chunks (issued ~6 phases ago), then adapter K=32 MFMA
    VMG("vmcnt(0)"); SCHEDB; SBAR; SCHEDB;
    {
        const bf16_t* A0 = &lds[0][0][0];
        const bf16_t* B0 = &lds[0][2][0];
        bf16x8 aa[8]; bf16x8 bb[4];
#pragma unroll
        for (int ai = 0; ai < 8; ++ai) {
            int row = (ai >> 2) * 128 + wm * 64 + (ai & 3) * 16 + l15;
            aa[ai] = *(const bf16x8*)(A0 + row * 32 + l4 * 8);
        }
#pragma unroll
        for (int bj = 0; bj < 4; ++bj) {
            int row = (bj >> 1) * 128 + wn * 32 + (bj & 1) * 16 + l15;
            bb[bj] = *(const bf16x8*)(B0 + row * 32 + l4 * 8);
        }
        LGKM0; SCHEDB;
#pragma unroll
        for (int ai = 0; ai < 8; ++ai)
#pragma unroll
            for (int bj = 0; bj < 4; ++bj)
                acc[ai][bj] = __builtin_amdgcn_mfma_f32_16x16x32_bf16(
                    aa[ai], bb[bj], acc[ai][bj], 0, 0, 0);
    }

    // ---- epilogue: + bias, store f32 ----
#pragma unroll
    for (int ai = 0; ai < 8; ++ai) {
        int gm = row0 + (ai >> 2) * 128 + wm * 64 + (ai & 3) * 16 + l4 * 4;
#pragma unroll
        for (int bj = 0; bj < 4; ++bj) {
            int gn = col0 + (bj >> 1) * 128 + wn * 32 + (bj & 1) * 16 + l15;
            float bsv = bias[gn];
#pragma unroll
            for (int q = 0; q < 4; ++q)
                out[(size_t)(gm + q) * DOUT + gn] = acc[ai][bj][q] + bsv;
        }
    }
}

// ------------------------------------------------------------------
// Fallback GEMM (m97 structure) for small-workspace paths
// ------------------------------------------------------------------
template<bool WPRE>
__global__ __launch_bounds__(256) void gemm_kernel(
    const float* __restrict__ xf,
    const float* __restrict__ Wf, const bf16_t* __restrict__ Wb,
    const float* __restrict__ bias,
    const bf16_t* __restrict__ tpad, const bf16_t* __restrict__ Btp,
    float* __restrict__ out) {
    __shared__ __align__(16) bf16_t As[128 * 64];
    __shared__ __align__(16) bf16_t Bs[128 * 64];

    int orig = blockIdx.x;
    int id = (orig & 7) * 512 + (orig >> 3);
    int mb = id >> 5, nb = id & 31;
    int row0 = mb * 128, col0 = nb * 128;
    int b = row0 >> 11;

    int tid = threadIdx.x;
    int w = tid >> 6, l = tid & 63;
    int wm = w >> 1, wn = w & 1;

    f32x4 acc[4][4] = {};

    for (int k0 = 0; k0 < DIN; k0 += 64) {
#pragma unroll
        for (int i = 0; i < 4; ++i) {
            int flat = i * 256 + tid;
            int row = flat >> 3, c8 = flat & 7;
            const float* src = xf + (size_t)(row0 + row) * DIN + k0 + c8 * 8;
            float4 v0 = *(const float4*)src;
            float4 v1 = *(const float4*)(src + 4);
            *(bf16x8*)(&As[flat * 8]) = cvt8(v0, v1);
        }
        if constexpr (WPRE) {
#pragma unroll
            for (int i = 0; i < 4; ++i) {
                int flat = i * 256 + tid;
                int row = flat >> 3, c8 = flat & 7;
                __builtin_amdgcn_global_load_lds(
                    GLP(Wb + (size_t)(col0 + row) * DIN + k0 + c8 * 8),
                    LDSP(&Bs[flat * 8]), 16, 0, 0);
            }
        } else {
#pragma unroll
            for (int i = 0; i < 4; ++i) {
                int flat = i * 256 + tid;
                int row = flat >> 3, c8 = flat & 7;
                const float* src = Wf + (size_t)(col0 + row) * DIN + k0 + c8 * 8;
                float4 v0 = *(const float4*)src;
                float4 v1 = *(const float4*)(src + 4);
                *(bf16x8*)(&Bs[flat * 8]) = cvt8(v0, v1);
            }
        }
        __syncthreads();
#pragma unroll
        for (int s = 0; s < 2; ++s) {
            int kr = s * 32 + (l >> 4) * 8;
            bf16x8 a[4], bf[4];
#pragma unroll
            for (int i = 0; i < 4; ++i)
                a[i] = *(const bf16x8*)(&As[(wm * 64 + i * 16 + (l & 15)) * 64 + kr]);
#pragma unroll
            for (int j = 0; j < 4; ++j)
                bf[j] = *(const bf16x8*)(&Bs[(wn * 64 + j * 16 + (l & 15)) * 64 + kr]);
#pragma unroll
            for (int i = 0; i < 4; ++i)
#pragma unroll
                for (int j = 0; j < 4; ++j)
                    acc[i][j] = __builtin_amdgcn_mfma_f32_16x16x32_bf16(a[i], bf[j], acc[i][j], 0, 0, 0);
        }
        __syncthreads();
    }

    {
#pragma unroll
        for (int i = 0; i < 2; ++i) {
            int flat = i * 256 + tid;
            int row = flat >> 2, c8 = flat & 3;
            __builtin_amdgcn_global_load_lds(
                GLP(tpad + (size_t)(row0 + row) * 32 + c8 * 8),
                LDSP(&As[flat * 8]), 16, 0, 0);
            __builtin_amdgcn_global_load_lds(
                GLP(Btp + ((size_t)b * DOUT + col0 + row) * 32 + c8 * 8),
                LDSP(&Bs[flat * 8]), 16, 0, 0);
        }
        __syncthreads();
        int kr = (l >> 4) * 8;
        bf16x8 a[4], bf[4];
#pragma unroll
        for (int i = 0; i < 4; ++i)
            a[i] = *(const bf16x8*)(&As[(wm * 64 + i * 16 + (l & 15)) * 32 + kr]);
#pragma unroll
        for (int j = 0; j < 4; ++j)
            bf[j] = *(const bf16x8*)(&Bs[(wn * 64 + j * 16 + (l & 15)) * 32 + kr]);
#pragma unroll
        for (int i = 0; i < 4; ++i)
#pragma unroll
            for (int j = 0; j < 4; ++j)
                acc[i][j] = __builtin_amdgcn_mfma_f32_16x16x32_bf16(a[i], bf[j], acc[i][j], 0, 0, 0);
    }

#pragma unroll
    for (int i = 0; i < 4; ++i) {
        int gm = row0 + wm * 64 + i * 16 + (l >> 4) * 4;
#pragma unroll
        for (int j = 0; j < 4; ++j) {
            int gn = col0 + wn * 64 + j * 16 + (l & 15);
            float bs = bias[gn];
#pragma unroll
            for (int q = 0; q < 4; ++q)
                out[(size_t)(gm + q) * DOUT + gn] = acc[i][j][q] + bs;
        }
    }
}

// ------------------------------------------------------------------
extern "C" void kernel_launch(void* const* d_in, const int* in_sizes, int n_in,
                              void* d_out, int out_size, void* d_ws, size_t ws_size,
                              hipStream_t stream) {
    const float* x        = (const float*)d_in[0];
    const int*   task_ids = (const int*)d_in[1];
    const float* W        = (const float*)d_in[2];
    const float* bias     = (const float*)d_in[3];
    const float* logits   = (const float*)d_in[4];
    const float* lora_a   = (const float*)d_in[5];
    const float* lora_b   = (const float*)d_in[6];
    float* out = (float*)d_out;

    char* ws = (char*)d_ws;
    size_t off = 0;
    auto alloc = [&](size_t bytes) {
        char* p = ws + off;
        off += (bytes + 255) & ~(size_t)255;
        return p;
    };
    bf16_t* Abt  = (bf16_t*)alloc((size_t)BS * RANK * DIN * 2);
    bf16_t* Btp  = (bf16_t*)alloc((size_t)BS * DOUT * 32 * 2);
    bf16_t* tpad = (bf16_t*)alloc((size_t)MTOT * 32 * 2);
    bf16_t* Wb   = (bf16_t*)alloc((size_t)DOUT * DIN * 2);
    size_t w_end = off;
    bf16_t* xb   = (bf16_t*)alloc((size_t)MTOT * DIN * 2);
    size_t full_end = off;

    bool wpre = ws_size >= w_end;
    bool xpre = ws_size >= full_end;

    mix_kernel<<<dim3(64, 8), 256, 0, stream>>>(logits, task_ids, lora_a, lora_b, Abt, Btp);
    if (wpre)
        convw_kernel<<<(DOUT * DIN / 8) / 256, 256, 0, stream>>>(W, Wb);
    if (xpre)
        tconv_kernel<true><<<MTOT / 64, 256, 0, stream>>>(x, Abt, xb, tpad);
    else
        tconv_kernel<false><<<MTOT / 64, 256, 0, stream>>>(x, Abt, nullptr, tpad);

    if (xpre) {
        int nblk = (MTOT / 256) * (DOUT / 256);   // 1024
        gemm8_kernel<<<nblk, 512, 0, stream>>>(xb, Wb, bias, tpad, Btp, out);
    } else {
        int nblk = (MTOT / 128) * (DOUT / 128);   // 4096
        if (wpre)
            gemm_kernel<true><<<nblk, 256, 0, stream>>>(x, W, Wb, bias, tpad, Btp, out);
        else
            gemm_kernel<false><<<nblk, 256, 0, stream>>>(x, W, Wb, bias, tpad, Btp, out);
    }
}

// Round 13
// 686.980 us; speedup vs baseline: 1.4518x; 1.4518x over previous
//
#include <hip/hip_runtime.h>
#include <hip/hip_bf16.h>
#include <cstdint>
#include <cstddef>

typedef __bf16 bf16_t;
typedef __bf16 bf16x8 __attribute__((ext_vector_type(8)));
typedef float f32x4 __attribute__((ext_vector_type(4)));

#define GLP(p)  (const __attribute__((address_space(1))) void*)(p)
#define LDSP(p) (__attribute__((address_space(3))) void*)(p)

static constexpr int BS   = 8;
static constexpr int SEQ  = 2048;
static constexpr int DIN  = 4096;
static constexpr int DOUT = 4096;
static constexpr int NSK  = 8;
static constexpr int RANK = 16;
static constexpr int MTOT = BS * SEQ;           // 16384
static constexpr int NKT  = 128;                // 4096 / 32 K-tiles (+1 adapter)

static __device__ __forceinline__ bf16x8 cvt8(float4 v0, float4 v1) {
    bf16x8 o;
    o[0] = (bf16_t)v0.x; o[1] = (bf16_t)v0.y; o[2] = (bf16_t)v0.z; o[3] = (bf16_t)v0.w;
    o[4] = (bf16_t)v1.x; o[5] = (bf16_t)v1.y; o[6] = (bf16_t)v1.z; o[7] = (bf16_t)v1.w;
    return o;
}

// ------------------------------------------------------------------
// Kernel 1: mixing weights -> Abt (bf16 [b][16][4096]) and
//           Btp (bf16 [b][4096][32], r>=16 zero)
// ------------------------------------------------------------------
__global__ __launch_bounds__(256) void mix_kernel(
    const float* __restrict__ logits, const int* __restrict__ task_ids,
    const float* __restrict__ lora_a, const float* __restrict__ lora_b,
    bf16_t* __restrict__ Abt, bf16_t* __restrict__ Btp) {
    int b = blockIdx.y;
    int c = blockIdx.x;
    int tid = threadIdx.x;

    int t = task_ids[b];
    float w[NSK]; float sum = 0.f;
#pragma unroll
    for (int s = 0; s < NSK; ++s) {
        float lg = logits[t * NSK + s];
        float sg = 1.f / (1.f + __expf(-lg));
        w[s] = sg; sum += sg;
    }
    float inv = 1.f / (sum + 1e-12f);
#pragma unroll
    for (int s = 0; s < NSK; ++s) w[s] *= inv;

    {
        int r = tid & 15, kk = tid >> 4;
#pragma unroll
        for (int i = 0; i < 4; ++i) {
            int k = c * 64 + i * 16 + kk;
            float acc = 0.f;
#pragma unroll
            for (int s = 0; s < NSK; ++s)
                acc += w[s] * lora_a[((size_t)s * DIN + k) * RANK + r];
            Abt[((size_t)b * RANK + r) * DIN + k] = (bf16_t)acc;
        }
    }
    {
        int n = c * 64 + (tid & 63);
        int r0 = tid >> 6;
#pragma unroll
        for (int i = 0; i < 4; ++i) {
            int rr = r0 + i * 4;
            float acc = 0.f;
#pragma unroll
            for (int s = 0; s < NSK; ++s)
                acc += w[s] * lora_b[((size_t)s * RANK + rr) * DOUT + n];
            Btp[((size_t)b * DOUT + n) * 32 + rr] = (bf16_t)acc;
            Btp[((size_t)b * DOUT + n) * 32 + 16 + rr] = (bf16_t)0.f;
        }
    }
}

// ------------------------------------------------------------------
// Kernel 2: W f32 -> bf16
// ------------------------------------------------------------------
__global__ __launch_bounds__(256) void convw_kernel(const float* __restrict__ W,
                                                    bf16_t* __restrict__ Wb) {
    size_t g = (size_t)blockIdx.x * 256 + threadIdx.x;
    const float4* src = (const float4*)W;
    float4 v0 = src[g * 2], v1 = src[g * 2 + 1];
    *(bf16x8*)(Wb + g * 8) = cvt8(v0, v1);
}

// ------------------------------------------------------------------
// Kernel 3: fused x->bf16 conversion + t = (x @ A_mix)/16, padded to K=32
// ------------------------------------------------------------------
template<bool XPRE>
__global__ __launch_bounds__(256) void tconv_kernel(
    const float* __restrict__ x, const bf16_t* __restrict__ Abt,
    bf16_t* __restrict__ xb, bf16_t* __restrict__ tpad) {
    __shared__ __align__(16) bf16_t As[64 * 64];
    __shared__ __align__(16) bf16_t Aa[16 * 64];

    int row0 = blockIdx.x * 64;
    int b = row0 >> 11;
    int tid = threadIdx.x;
    int w = tid >> 6, l = tid & 63;
    const bf16_t* Ab = Abt + (size_t)b * RANK * DIN;

    f32x4 acc = {0.f, 0.f, 0.f, 0.f};

    for (int k0 = 0; k0 < DIN; k0 += 64) {
#pragma unroll
        for (int i = 0; i < 2; ++i) {
            int flat = i * 256 + tid;
            int row = flat >> 3, c8 = flat & 7;
            const float* src = x + (size_t)(row0 + row) * DIN + k0 + c8 * 8;
            float4 v0 = *(const float4*)src;
            float4 v1 = *(const float4*)(src + 4);
            bf16x8 o = cvt8(v0, v1);
            *(bf16x8*)(&As[flat * 8]) = o;
            if (XPRE)
                *(bf16x8*)(xb + (size_t)(row0 + row) * DIN + k0 + c8 * 8) = o;
        }
        if (tid < 128) {
            int r = tid >> 3, c8 = tid & 7;
            __builtin_amdgcn_global_load_lds(GLP(Ab + (size_t)r * DIN + k0 + c8 * 8),
                                             LDSP(&Aa[tid * 8]), 16, 0, 0);
        }
        __syncthreads();
#pragma unroll
        for (int s = 0; s < 2; ++s) {
            int kr = s * 32 + (l >> 4) * 8;
            bf16x8 a = *(const bf16x8*)(&As[(w * 16 + (l & 15)) * 64 + kr]);
            bf16x8 bb = *(const bf16x8*)(&Aa[(l & 15) * 64 + kr]);
            acc = __builtin_amdgcn_mfma_f32_16x16x32_bf16(a, bb, acc, 0, 0, 0);
        }
        __syncthreads();
    }
    int r = l & 15;
    int rowb = w * 16 + (l >> 4) * 4;
#pragma unroll
    for (int j = 0; j < 4; ++j) {
        int gm = row0 + rowb + j;
        tpad[(size_t)gm * 32 + r] = (bf16_t)(acc[j] * 0.0625f);
        tpad[(size_t)gm * 32 + 16 + r] = (bf16_t)0.f;
    }
}

// ------------------------------------------------------------------
// Kernel 4: 256x128 tile, BK=32, 4 waves (2x2), 48 KiB LDS -> 2 blocks/CU.
//   R7 sync skeleton: per tile {barrier; stageA(next,4); vmcnt(4); barrier;
//   body = 12 ds_read + 32 MFMA + stageB(next,2)}. Two co-resident blocks
//   per CU provide the DS<->MFMA overlap a single barrier group can't.
//   Adapter = 129th K-tile (tpad 256x32 / Btp 128x32, same shape).
// ------------------------------------------------------------------
#define SBAR   __builtin_amdgcn_s_barrier()
#define SCHEDB __builtin_amdgcn_sched_barrier(0)
#define VMG(TXT) asm volatile("s_waitcnt " TXT ::: "memory")

__global__ __launch_bounds__(256, 2) void gemm3_kernel(
    const bf16_t* __restrict__ xb, const bf16_t* __restrict__ Wb,
    const float* __restrict__ bias,
    const bf16_t* __restrict__ tpad, const bf16_t* __restrict__ Btp,
    float* __restrict__ out) {
    // per buffer: A 256x32 (8192 elems) + B 128x32 (4096 elems) = 24 KiB
    __shared__ __align__(16) bf16_t lds[2][12288];   // 48 KiB

    int tid = threadIdx.x;
    int w = tid >> 6, l = tid & 63;
    int wm = w >> 1, wn = w & 1;        // 2M x 2N waves
    int l4 = l >> 4, l15 = l & 15;

    // XCD-bijective swizzle: nwg = 2048, 8 XCDs, 256 per XCD
    int orig = blockIdx.x;
    int id = (orig & 7) * 256 + (orig >> 3);
    int mb = id >> 5, nb = id & 31;     // 64 x 32
    int row0 = mb * 256, col0 = nb * 128;
    int b = row0 >> 11;

    f32x4 acc[8][4] = {};

    // stage A chunk (256 rows x 32 k = 16 KiB): 4 loads/thread.
    // Dest linear; source chunk pre-swizzled sc = ch ^ (r&3) (rule 21).
    auto stageA = [&](const bf16_t* base, size_t rstride, int c) {
#pragma unroll
        for (int ld = 0; ld < 4; ++ld) {
            int flat = ld * 256 + tid;       // 0..1023
            int r = flat >> 2, ch = flat & 3;
            int sc = ch ^ (r & 3);
            __builtin_amdgcn_global_load_lds(
                GLP(base + (size_t)r * rstride + sc * 8),
                LDSP(&lds[c][flat * 8]), 16, 0, 0);
        }
    };
    // stage B chunk (128 rows x 32 k = 8 KiB): 2 loads/thread.
    auto stageB = [&](const bf16_t* base, size_t rstride, int c) {
#pragma unroll
        for (int ld = 0; ld < 2; ++ld) {
            int flat = ld * 256 + tid;       // 0..511
            int r = flat >> 2, ch = flat & 3;
            int sc = ch ^ (r & 3);
            __builtin_amdgcn_global_load_lds(
                GLP(base + (size_t)r * rstride + sc * 8),
                LDSP(&lds[c][8192 + flat * 8]), 16, 0, 0);
        }
    };

    auto loadAfrag = [&](int c, int i) {
        int row = wm * 128 + i * 16 + l15;
        return *(const bf16x8*)(&lds[c][row * 32 + ((l4 ^ (row & 3)) << 3)]);
    };
    auto loadBfrag = [&](int c, int jj) {
        int row = wn * 64 + jj * 16 + l15;
        return *(const bf16x8*)(&lds[c][8192 + row * 32 + ((l4 ^ (row & 3)) << 3)]);
    };

    const bf16_t* Abase = xb + (size_t)row0 * DIN;
    const bf16_t* Bbase = Wb + (size_t)col0 * DIN;
    const bf16_t* AbaseAdp = tpad + (size_t)row0 * 32;
    const bf16_t* BbaseAdp = Btp + ((size_t)b * DOUT + col0) * 32;

    // prologue: tile 0 fully staged (6 loads in flight)
    stageA(Abase, DIN, 0);
    stageB(Bbase, DIN, 0);

#pragma unroll 1
    for (int j = 0; j <= NKT; ++j) {
        int c = j & 1;
        // barrier #1: all waves done READING buf[c^1] (body of iter j-1)
        SCHEDB; SBAR; SCHEDB;
        if (j < NKT) {
            int jn = j + 1;
            if (jn < NKT) stageA(Abase + jn * 32, DIN, c ^ 1);
            else          stageA(AbaseAdp, 32, c ^ 1);
            // tile j's 6 loads are the oldest; 4 new stay in flight
            VMG("vmcnt(4)");
        } else {
            VMG("vmcnt(0)");
        }
        SCHEDB;
        // barrier #2: every wave's tile-j stage has landed
        SBAR; SCHEDB;

        // ---- straight-line body: 12 ds_read + 32 MFMA + stageB(next) ----
        bf16x8 a0[4], a1[4], b0[2], b1[2];
#pragma unroll
        for (int i = 0; i < 4; ++i) a0[i] = loadAfrag(c, i);
#pragma unroll
        for (int jj = 0; jj < 2; ++jj) b0[jj] = loadBfrag(c, jj);
        if (j < NKT) {
            int jn = j + 1;
            if (jn < NKT) stageB(Bbase + jn * 32, DIN, c ^ 1);
            else          stageB(BbaseAdp, 32, c ^ 1);
        }
        // quadrant (0,0)
#pragma unroll
        for (int i = 0; i < 4; ++i)
#pragma unroll
            for (int jj = 0; jj < 2; ++jj)
                acc[i][jj] = __builtin_amdgcn_mfma_f32_16x16x32_bf16(
                    a0[i], b0[jj], acc[i][jj], 0, 0, 0);
#pragma unroll
        for (int jj = 0; jj < 2; ++jj) b1[jj] = loadBfrag(c, 2 + jj);
        // quadrant (0,1)
#pragma unroll
        for (int i = 0; i < 4; ++i)
#pragma unroll
            for (int jj = 0; jj < 2; ++jj)
                acc[i][2 + jj] = __builtin_amdgcn_mfma_f32_16x16x32_bf16(
                    a0[i], b1[jj], acc[i][2 + jj], 0, 0, 0);
#pragma unroll
        for (int i = 0; i < 4; ++i) a1[i] = loadAfrag(c, 4 + i);
        // quadrant (1,1)
#pragma unroll
        for (int i = 0; i < 4; ++i)
#pragma unroll
            for (int jj = 0; jj < 2; ++jj)
                acc[4 + i][2 + jj] = __builtin_amdgcn_mfma_f32_16x16x32_bf16(
                    a1[i], b1[jj], acc[4 + i][2 + jj], 0, 0, 0);
        // quadrant (1,0) — b0 still live
#pragma unroll
        for (int i = 0; i < 4; ++i)
#pragma unroll
            for (int jj = 0; jj < 2; ++jj)
                acc[4 + i][jj] = __builtin_amdgcn_mfma_f32_16x16x32_bf16(
                    a1[i], b0[jj], acc[4 + i][jj], 0, 0, 0);
    }

    // ---- epilogue: + bias, store f32 ----
#pragma unroll
    for (int i = 0; i < 8; ++i) {
        int gm = row0 + wm * 128 + i * 16 + l4 * 4;
#pragma unroll
        for (int jj = 0; jj < 4; ++jj) {
            int gn = col0 + wn * 64 + jj * 16 + l15;
            float bsv = bias[gn];
#pragma unroll
            for (int q = 0; q < 4; ++q)
                out[(size_t)(gm + q) * DOUT + gn] = acc[i][jj][q] + bsv;
        }
    }
}

// ------------------------------------------------------------------
// Fallback GEMM (m97 structure) for small-workspace paths
// ------------------------------------------------------------------
template<bool WPRE>
__global__ __launch_bounds__(256) void gemm_kernel(
    const float* __restrict__ xf,
    const float* __restrict__ Wf, const bf16_t* __restrict__ Wb,
    const float* __restrict__ bias,
    const bf16_t* __restrict__ tpad, const bf16_t* __restrict__ Btp,
    float* __restrict__ out) {
    __shared__ __align__(16) bf16_t As[128 * 64];
    __shared__ __align__(16) bf16_t Bs[128 * 64];

    int orig = blockIdx.x;
    int id = (orig & 7) * 512 + (orig >> 3);
    int mb = id >> 5, nb = id & 31;
    int row0 = mb * 128, col0 = nb * 128;
    int b = row0 >> 11;

    int tid = threadIdx.x;
    int w = tid >> 6, l = tid & 63;
    int wm = w >> 1, wn = w & 1;

    f32x4 acc[4][4] = {};

    for (int k0 = 0; k0 < DIN; k0 += 64) {
#pragma unroll
        for (int i = 0; i < 4; ++i) {
            int flat = i * 256 + tid;
            int row = flat >> 3, c8 = flat & 7;
            const float* src = xf + (size_t)(row0 + row) * DIN + k0 + c8 * 8;
            float4 v0 = *(const float4*)src;
            float4 v1 = *(const float4*)(src + 4);
            *(bf16x8*)(&As[flat * 8]) = cvt8(v0, v1);
        }
        if constexpr (WPRE) {
#pragma unroll
            for (int i = 0; i < 4; ++i) {
                int flat = i * 256 + tid;
                int row = flat >> 3, c8 = flat & 7;
                __builtin_amdgcn_global_load_lds(
                    GLP(Wb + (size_t)(col0 + row) * DIN + k0 + c8 * 8),
                    LDSP(&Bs[flat * 8]), 16, 0, 0);
            }
        } else {
#pragma unroll
            for (int i = 0; i < 4; ++i) {
                int flat = i * 256 + tid;
                int row = flat >> 3, c8 = flat & 7;
                const float* src = Wf + (size_t)(col0 + row) * DIN + k0 + c8 * 8;
                float4 v0 = *(const float4*)src;
                float4 v1 = *(const float4*)(src + 4);
                *(bf16x8*)(&Bs[flat * 8]) = cvt8(v0, v1);
            }
        }
        __syncthreads();
#pragma unroll
        for (int s = 0; s < 2; ++s) {
            int kr = s * 32 + (l >> 4) * 8;
            bf16x8 a[4], bf[4];
#pragma unroll
            for (int i = 0; i < 4; ++i)
                a[i] = *(const bf16x8*)(&As[(wm * 64 + i * 16 + (l & 15)) * 64 + kr]);
#pragma unroll
            for (int j = 0; j < 4; ++j)
                bf[j] = *(const bf16x8*)(&Bs[(wn * 64 + j * 16 + (l & 15)) * 64 + kr]);
#pragma unroll
            for (int i = 0; i < 4; ++i)
#pragma unroll
                for (int j = 0; j < 4; ++j)
                    acc[i][j] = __builtin_amdgcn_mfma_f32_16x16x32_bf16(a[i], bf[j], acc[i][j], 0, 0, 0);
        }
        __syncthreads();
    }

    {
#pragma unroll
        for (int i = 0; i < 2; ++i) {
            int flat = i * 256 + tid;
            int row = flat >> 2, c8 = flat & 3;
            __builtin_amdgcn_global_load_lds(
                GLP(tpad + (size_t)(row0 + row) * 32 + c8 * 8),
                LDSP(&As[flat * 8]), 16, 0, 0);
            __builtin_amdgcn_global_load_lds(
                GLP(Btp + ((size_t)b * DOUT + col0 + row) * 32 + c8 * 8),
                LDSP(&Bs[flat * 8]), 16, 0, 0);
        }
        __syncthreads();
        int kr = (l >> 4) * 8;
        bf16x8 a[4], bf[4];
#pragma unroll
        for (int i = 0; i < 4; ++i)
            a[i] = *(const bf16x8*)(&As[(wm * 64 + i * 16 + (l & 15)) * 32 + kr]);
#pragma unroll
        for (int j = 0; j < 4; ++j)
            bf[j] = *(const bf16x8*)(&Bs[(wn * 64 + j * 16 + (l & 15)) * 32 + kr]);
#pragma unroll
        for (int i = 0; i < 4; ++i)
#pragma unroll
            for (int j = 0; j < 4; ++j)
                acc[i][j] = __builtin_amdgcn_mfma_f32_16x16x32_bf16(a[i], bf[j], acc[i][j], 0, 0, 0);
    }

#pragma unroll
    for (int i = 0; i < 4; ++i) {
        int gm = row0 + wm * 64 + i * 16 + (l >> 4) * 4;
#pragma unroll
        for (int j = 0; j < 4; ++j) {
            int gn = col0 + wn * 64 + j * 16 + (l & 15);
            float bs = bias[gn];
#pragma unroll
            for (int q = 0; q < 4; ++q)
                out[(size_t)(gm + q) * DOUT + gn] = acc[i][j][q] + bs;
        }
    }
}

// ------------------------------------------------------------------
extern "C" void kernel_launch(void* const* d_in, const int* in_sizes, int n_in,
                              void* d_out, int out_size, void* d_ws, size_t ws_size,
                              hipStream_t stream) {
    const float* x        = (const float*)d_in[0];
    const int*   task_ids = (const int*)d_in[1];
    const float* W        = (const float*)d_in[2];
    const float* bias     = (const float*)d_in[3];
    const float* logits   = (const float*)d_in[4];
    const float* lora_a   = (const float*)d_in[5];
    const float* lora_b   = (const float*)d_in[6];
    float* out = (float*)d_out;

    char* ws = (char*)d_ws;
    size_t off = 0;
    auto alloc = [&](size_t bytes) {
        char* p = ws + off;
        off += (bytes + 255) & ~(size_t)255;
        return p;
    };
    bf16_t* Abt  = (bf16_t*)alloc((size_t)BS * RANK * DIN * 2);
    bf16_t* Btp  = (bf16_t*)alloc((size_t)BS * DOUT * 32 * 2);
    bf16_t* tpad = (bf16_t*)alloc((size_t)MTOT * 32 * 2);
    bf16_t* Wb   = (bf16_t*)alloc((size_t)DOUT * DIN * 2);
    size_t w_end = off;
    bf16_t* xb   = (bf16_t*)alloc((size_t)MTOT * DIN * 2);
    size_t full_end = off;

    bool wpre = ws_size >= w_end;
    bool xpre = ws_size >= full_end;

    mix_kernel<<<dim3(64, 8), 256, 0, stream>>>(logits, task_ids, lora_a, lora_b, Abt, Btp);
    if (wpre)
        convw_kernel<<<(DOUT * DIN / 8) / 256, 256, 0, stream>>>(W, Wb);
    if (xpre)
        tconv_kernel<true><<<MTOT / 64, 256, 0, stream>>>(x, Abt, xb, tpad);
    else
        tconv_kernel<false><<<MTOT / 64, 256, 0, stream>>>(x, Abt, nullptr, tpad);

    if (xpre) {
        int nblk = (MTOT / 256) * (DOUT / 128);   // 2048
        gemm3_kernel<<<nblk, 256, 0, stream>>>(xb, Wb, bias, tpad, Btp, out);
    } else {
        int nblk = (MTOT / 128) * (DOUT / 128);   // 4096
        if (wpre)
            gemm_kernel<true><<<nblk, 256, 0, stream>>>(x, W, Wb, bias, tpad, Btp, out);
        else
            gemm_kernel<false><<<nblk, 256, 0, stream>>>(x, W, Wb, bias, tpad, Btp, out);
    }
}